// Round 7
// baseline (917.006 us; speedup 1.0000x reference)
//
#include <hip/hip_runtime.h>
#include <hip/hip_bf16.h>

// GCN 2-layer: relu(A_hat @ relu(A_hat @ X @ W1 + b1) @ W2 + b2)
//   L1: aggregate X (256f) -> split-bf16; MFMA GEMM W1 (+b1, relu) -> split-bf16 H
//   L2: MFMA GEMM W2 (epilogue: *dinv) -> fp32 Ys; aggregate Ys (250f) + b2 + relu
//   GEMMs: bf16 MFMA with hi/lo split precision (3 products), ~2^-16 rel error.
//   Aggregation: pull via per-call CSR of int2{r, dinv[r]} — 2-deep load chain,
//   wave-per-node, 8-deep batched gathers.

#define F_IN  256
#define F_HID 512
#define F_OUT 250

using bf16x8 = __attribute__((ext_vector_type(8))) short;
using f32x4  = __attribute__((ext_vector_type(4))) float;

__device__ __forceinline__ ushort f32_bf16_rne(float f) {
    uint u = __float_as_uint(f);
    u += 0x7FFFu + ((u >> 16) & 1u);
    return (ushort)(u >> 16);
}
__device__ __forceinline__ float bf16u_f32(ushort h) {
    return __uint_as_float(((uint)h) << 16);
}

// ---------------- CSR build ----------------

__global__ __launch_bounds__(256) void hist_kernel(const int* __restrict__ col, int* cnt, int E) {
    int e = blockIdx.x * 256 + threadIdx.x;
    if (e < E) atomicAdd(&cnt[col[e]], 1);
}

__global__ __launch_bounds__(256) void dinv_kernel(const int* __restrict__ cnt, float* dinv, int n) {
    int i = blockIdx.x * 256 + threadIdx.x;
    if (i < n) dinv[i] = rsqrtf((float)(cnt[i] + 1));  // +1 self loop
}

__global__ __launch_bounds__(1024) void scan_kernel(const int* __restrict__ cnt, int* rowptr, int n) {
    __shared__ int wsum[16];
    __shared__ int carry_s;
    int t = threadIdx.x;
    int wid = t >> 6, lane = t & 63;
    if (t == 0) carry_s = 0;
    __syncthreads();
    for (int base = 0; base < n; base += 1024) {
        int i = base + t;
        int v = (i < n) ? cnt[i] : 0;
        int s = v;
        #pragma unroll
        for (int off = 1; off < 64; off <<= 1) {
            int u = __shfl_up(s, off, 64);
            if (lane >= off) s += u;
        }
        if (lane == 63) wsum[wid] = s;
        __syncthreads();
        if (wid == 0 && lane < 16) {
            int ws = wsum[lane];
            #pragma unroll
            for (int off = 1; off < 16; off <<= 1) {
                int u = __shfl_up(ws, off, 64);
                if (lane >= off) ws += u;
            }
            wsum[lane] = ws;
        }
        __syncthreads();
        int wbase = (wid == 0) ? 0 : wsum[wid - 1];
        int carry = carry_s;
        if (i < n) rowptr[i] = carry + wbase + s - v;
        __syncthreads();
        if (t == 1023) carry_s = carry + wbase + s;
        __syncthreads();
    }
    if (t == 0) rowptr[n] = carry_s;
}

// csrd[p] = {source row r, bits(dinv[r])} — one 8B load per edge in agg.
__global__ __launch_bounds__(256) void fill_kernel(const int* __restrict__ row, const int* __restrict__ col,
                                                   const int* __restrict__ rowptr, int* cursor,
                                                   const float* __restrict__ dinv,
                                                   int2* __restrict__ csrd, int E) {
    int e = blockIdx.x * 256 + threadIdx.x;
    if (e < E) {
        int c = col[e];
        int r = row[e];
        int p = rowptr[c] + atomicAdd(&cursor[c], 1);
        csrd[p] = make_int2(r, __float_as_int(dinv[r]));
    }
}

// ---------------- W transpose + split:  W[K][N] fp32 -> WT_hi/lo [N][K] bf16 ----------------
// Scalar global loads: W rows may be only 4B-aligned (N=250). Tiny kernel, runs once.

__global__ __launch_bounds__(256) void wsplit_kernel(const float* __restrict__ W,
                                                     ushort* __restrict__ WThi, ushort* __restrict__ WTlo,
                                                     int K, int N) {
    __shared__ float tile[32][33];
    int t = threadIdx.x;
    int k0 = blockIdx.x * 32, n0 = blockIdx.y * 32;
    int r = t >> 3, c = (t & 7) * 4;
    #pragma unroll
    for (int q = 0; q < 4; ++q) {
        float z = 0.f;
        if (n0 + c + q < N) z = W[(size_t)(k0 + r) * N + n0 + c + q];
        tile[r][c + q] = z;
    }
    __syncthreads();
    int nr = t >> 3, kq = (t & 7) * 4;
    int gn = n0 + nr;
    if (gn < N) {
        ushort4 h4, l4;
        ushort* hp = &h4.x; ushort* lp = &l4.x;
        #pragma unroll
        for (int q = 0; q < 4; ++q) {
            float z = tile[kq + q][nr];
            ushort h = f32_bf16_rne(z);
            hp[q] = h;
            lp[q] = f32_bf16_rne(z - bf16u_f32(h));
        }
        *(ushort4*)&WThi[(size_t)gn * K + k0 + kq] = h4;
        *(ushort4*)&WTlo[(size_t)gn * K + k0 + kq] = l4;
    }
}

// ---------------- aggregation: wave-per-node, float4/lane, 8-deep batched gathers ----
// PRESCALED=false: out[c] = dinv[c]*( sum dinv[r]*X[r] + dinv[c]*X[c] )
// PRESCALED=true : X rows already carry dinv[r]; out[c] = dinv[c]*( sum X[r] + X[c] )

template<int F, int LDX, bool BIAS_RELU, bool SPLIT_OUT, bool PRESCALED>
__global__ __launch_bounds__(256) void agg_kernel(const float* __restrict__ X,
                                                  const float* __restrict__ dinv,
                                                  const int* __restrict__ rowptr,
                                                  const int2* __restrict__ csrd,
                                                  const float* __restrict__ bias,
                                                  float* __restrict__ out,
                                                  ushort* __restrict__ outHi, ushort* __restrict__ outLo,
                                                  int ldo, int n) {
    int c = blockIdx.x * 4 + (threadIdx.x >> 6);
    if (c >= n) return;
    int l = threadIdx.x & 63;
    int f0 = l * 4;
    float dc = dinv[c];

    float4 acc;
    {
        float4 v = *(const float4*)(X + (size_t)c * LDX + f0);
        if (PRESCALED) { acc = v; }                       // already has dinv[c]
        else { acc.x = v.x * dc; acc.y = v.y * dc; acc.z = v.z * dc; acc.w = v.w * dc; }
    }

    int beg = rowptr[c], end = rowptr[c + 1];
    int j = beg;
    // batched-by-8: 8 independent 2-deep gather chains in flight
    for (; j + 8 <= end; j += 8) {
        int2 e8[8];
        #pragma unroll
        for (int q = 0; q < 8; ++q) e8[q] = csrd[j + q];
        float4 v[8];
        #pragma unroll
        for (int q = 0; q < 8; ++q)
            v[q] = *(const float4*)(X + (size_t)e8[q].x * LDX + f0);
        #pragma unroll
        for (int q = 0; q < 8; ++q) {
            if (PRESCALED) {
                acc.x += v[q].x; acc.y += v[q].y; acc.z += v[q].z; acc.w += v[q].w;
            } else {
                float dr = __int_as_float(e8[q].y);
                acc.x += dr * v[q].x; acc.y += dr * v[q].y;
                acc.z += dr * v[q].z; acc.w += dr * v[q].w;
            }
        }
    }
    for (; j < end; ++j) {
        int2 e = csrd[j];
        float4 v = *(const float4*)(X + (size_t)e.x * LDX + f0);
        if (PRESCALED) {
            acc.x += v.x; acc.y += v.y; acc.z += v.z; acc.w += v.w;
        } else {
            float dr = __int_as_float(e.y);
            acc.x += dr * v.x; acc.y += dr * v.y; acc.z += dr * v.z; acc.w += dr * v.w;
        }
    }
    acc.x *= dc; acc.y *= dc; acc.z *= dc; acc.w *= dc;

    if (SPLIT_OUT) {
        ushort4 h4, l4;
        float a4[4] = {acc.x, acc.y, acc.z, acc.w};
        ushort* hp = &h4.x; ushort* lp = &l4.x;
        #pragma unroll
        for (int q = 0; q < 4; ++q) {
            ushort h = f32_bf16_rne(a4[q]);
            hp[q] = h;
            lp[q] = f32_bf16_rne(a4[q] - bf16u_f32(h));
        }
        *(ushort4*)(outHi + (size_t)c * F + f0) = h4;
        *(ushort4*)(outLo + (size_t)c * F + f0) = l4;
        return;
    }

    float* op = out + (size_t)c * ldo + f0;
    if (BIAS_RELU) {
        float b[4];
        #pragma unroll
        for (int q = 0; q < 4; ++q) b[q] = (f0 + q < F) ? bias[f0 + q] : 0.f;
        acc.x = fmaxf(acc.x + b[0], 0.f);
        acc.y = fmaxf(acc.y + b[1], 0.f);
        acc.z = fmaxf(acc.z + b[2], 0.f);
        acc.w = fmaxf(acc.w + b[3], 0.f);
        if (f0 + 3 < F) {
            ((float2*)op)[0] = make_float2(acc.x, acc.y);
            ((float2*)op)[1] = make_float2(acc.z, acc.w);
        } else {
            float a4[4] = {acc.x, acc.y, acc.z, acc.w};
            #pragma unroll
            for (int q = 0; q < 4; ++q)
                if (f0 + q < F) op[q] = a4[q];
        }
    } else {
        *(float4*)op = acc;
    }
}

// ---------------- MFMA split-bf16 GEMM ----------------
// C[M,N] = (Ahi+Alo)[M,K] @ (Bhi+Blo)^T-stored[N,K]   (3-product split)
// BM=BN=128, BK=32, 256 thr (4 waves, 2x2), per-wave 64x64 = 4x4 frags of 16x16x32.
// SPLIT_OUT: +bias, relu, emit split-bf16 (ld = N). else: fp32 out *dinv[row], ldc param.

template<bool SPLIT_OUT>
__global__ __launch_bounds__(256) void gemm_mfma(const ushort* __restrict__ Ahi, const ushort* __restrict__ Alo,
                                                 const ushort* __restrict__ Bhi, const ushort* __restrict__ Blo,
                                                 const float* __restrict__ bias,
                                                 const float* __restrict__ dinv,
                                                 float* __restrict__ Cf,
                                                 ushort* __restrict__ Chi, ushort* __restrict__ Clo,
                                                 int M, int N, int K, int ldc) {
    __shared__ ushort As_hi[128][40];   // 80B rows: 16B-aligned, <=2-way bank alias
    __shared__ ushort As_lo[128][40];
    __shared__ ushort Bs_hi[128][40];
    __shared__ ushort Bs_lo[128][40];

    int t = threadIdx.x;
    int row0 = blockIdx.x * 128;
    int col0 = blockIdx.y * 128;
    int lane = t & 63;
    int w = t >> 6;
    int wr = w >> 1, wc = w & 1;       // wave 64x64 sub-tile
    int lr = lane & 15, lg = lane >> 4;

    int srow = t >> 2;                 // staging: 64 rows per pass
    int soct = (t & 3) * 8;            // k-octet within BK=32

    f32x4 acc[4][4];
    #pragma unroll
    for (int i = 0; i < 4; ++i)
        #pragma unroll
        for (int j = 0; j < 4; ++j)
            acc[i][j] = (f32x4){0.f, 0.f, 0.f, 0.f};

    for (int k0 = 0; k0 < K; k0 += 32) {
        #pragma unroll
        for (int h = 0; h < 2; ++h) {
            int r = srow + h * 64;
            int4 zero = make_int4(0, 0, 0, 0);
            int ga = row0 + r;
            int4 vh = zero, vl = zero;
            if (ga < M) {
                vh = *(const int4*)(Ahi + (size_t)ga * K + k0 + soct);
                vl = *(const int4*)(Alo + (size_t)ga * K + k0 + soct);
            }
            *(int4*)&As_hi[r][soct] = vh;
            *(int4*)&As_lo[r][soct] = vl;
            int gb = col0 + r;
            int4 wh = zero, wl = zero;
            if (gb < N) {
                wh = *(const int4*)(Bhi + (size_t)gb * K + k0 + soct);
                wl = *(const int4*)(Blo + (size_t)gb * K + k0 + soct);
            }
            *(int4*)&Bs_hi[r][soct] = wh;
            *(int4*)&Bs_lo[r][soct] = wl;
        }
        __syncthreads();

        bf16x8 ah[4], al[4], bh[4], bl[4];
        #pragma unroll
        for (int mi = 0; mi < 4; ++mi) {
            ah[mi] = *(const bf16x8*)&As_hi[wr * 64 + mi * 16 + lr][lg * 8];
            al[mi] = *(const bf16x8*)&As_lo[wr * 64 + mi * 16 + lr][lg * 8];
        }
        #pragma unroll
        for (int ni = 0; ni < 4; ++ni) {
            bh[ni] = *(const bf16x8*)&Bs_hi[wc * 64 + ni * 16 + lr][lg * 8];
            bl[ni] = *(const bf16x8*)&Bs_lo[wc * 64 + ni * 16 + lr][lg * 8];
        }
        #pragma unroll
        for (int mi = 0; mi < 4; ++mi)
            #pragma unroll
            for (int ni = 0; ni < 4; ++ni) {
                acc[mi][ni] = __builtin_amdgcn_mfma_f32_16x16x32_bf16(ah[mi], bh[ni], acc[mi][ni], 0, 0, 0);
                acc[mi][ni] = __builtin_amdgcn_mfma_f32_16x16x32_bf16(ah[mi], bl[ni], acc[mi][ni], 0, 0, 0);
                acc[mi][ni] = __builtin_amdgcn_mfma_f32_16x16x32_bf16(al[mi], bh[ni], acc[mi][ni], 0, 0, 0);
            }
        __syncthreads();
    }

    // epilogue: D lane map (verified): row=(lane>>4)*4+reg, col=lane&15
    #pragma unroll
    for (int mi = 0; mi < 4; ++mi) {
        int rbase = row0 + wr * 64 + mi * 16 + lg * 4;
        #pragma unroll
        for (int ni = 0; ni < 4; ++ni) {
            int cg = col0 + wc * 64 + ni * 16 + lr;
            f32x4 a = acc[mi][ni];
            if (SPLIT_OUT) {
                float bia = bias[cg];
                #pragma unroll
                for (int r = 0; r < 4; ++r) {
                    int rg = rbase + r;
                    if (rg < M) {
                        float z = fmaxf(a[r] + bia, 0.f);
                        ushort h = f32_bf16_rne(z);
                        Chi[(size_t)rg * N + cg] = h;
                        Clo[(size_t)rg * N + cg] = f32_bf16_rne(z - bf16u_f32(h));
                    }
                }
            } else {
                if (cg < N) {
                    #pragma unroll
                    for (int r = 0; r < 4; ++r) {
                        int rg = rbase + r;
                        if (rg < M) Cf[(size_t)rg * ldc + cg] = a[r] * dinv[rg];  // fold A_hat's dinv
                    }
                }
            }
        }
    }
}

// ---------------- launch ----------------

extern "C" void kernel_launch(void* const* d_in, const int* in_sizes, int n_in,
                              void* d_out, int out_size, void* d_ws, size_t ws_size,
                              hipStream_t stream) {
    const float* x   = (const float*)d_in[0];
    const int*   ei  = (const int*)d_in[1];
    const float* W1  = (const float*)d_in[2];
    const float* b1  = (const float*)d_in[3];
    const float* W2  = (const float*)d_in[4];
    const float* b2  = (const float*)d_in[5];
    float* out = (float*)d_out;

    const int n = in_sizes[0] / F_IN;
    const int E = in_sizes[1] / 2;
    const int* row = ei;
    const int* col = ei + E;

    char* p = (char*)d_ws;
    auto alloc = [&](size_t bytes) { void* r = (void*)p; p += (bytes + 255) & ~(size_t)255; return r; };
    int*    cnt    = (int*)alloc((size_t)n * 4);
    int*    cursor = (int*)alloc((size_t)n * 4);
    int*    rowptr = (int*)alloc((size_t)(n + 1) * 4);
    float*  dinv   = (float*)alloc((size_t)n * 4);
    int2*   csrd   = (int2*)alloc((size_t)E * 8);
    ushort* Ahi    = (ushort*)alloc((size_t)n * F_IN * 2);   // agg1 out (hi)
    ushort* Alo    = (ushort*)alloc((size_t)n * F_IN * 2);   // agg1 out (lo)
    ushort* Hhi    = (ushort*)alloc((size_t)n * F_HID * 2);  // gemm1 out (hi)
    ushort* Hlo    = (ushort*)alloc((size_t)n * F_HID * 2);
    ushort* W1Thi  = (ushort*)alloc((size_t)F_HID * F_IN * 2);
    ushort* W1Tlo  = (ushort*)alloc((size_t)F_HID * F_IN * 2);
    ushort* W2Thi  = (ushort*)alloc((size_t)F_OUT * F_HID * 2);
    ushort* W2Tlo  = (ushort*)alloc((size_t)F_OUT * F_HID * 2);
    float*  bufY   = (float*)Ahi;   // gemm2 out [n][256]; aliases Ahi+Alo (dead by then)

    int nb_n = (n + 255) / 256;
    int nb_e = (E + 255) / 256;

    // CSR build (cnt+cursor are adjacent carve-outs -> one memset covers both)
    hipMemsetAsync(cnt, 0, (char*)rowptr - (char*)cnt, stream);
    hist_kernel<<<nb_e, 256, 0, stream>>>(col, cnt, E);
    dinv_kernel<<<nb_n, 256, 0, stream>>>(cnt, dinv, n);
    scan_kernel<<<1, 1024, 0, stream>>>(cnt, rowptr, n);
    fill_kernel<<<nb_e, 256, 0, stream>>>(row, col, rowptr, cursor, dinv, csrd, E);

    // weight transpose+split
    {
        dim3 g1(F_IN / 32, F_HID / 32);
        wsplit_kernel<<<g1, 256, 0, stream>>>(W1, W1Thi, W1Tlo, F_IN, F_HID);
        dim3 g2(F_HID / 32, (F_OUT + 31) / 32);
        wsplit_kernel<<<g2, 256, 0, stream>>>(W2, W2Thi, W2Tlo, F_HID, F_OUT);
    }

    int nb_agg = (n + 3) / 4;

    // L1: aggregate X -> split bf16
    agg_kernel<F_IN, F_IN, false, true, false><<<nb_agg, 256, 0, stream>>>(
        x, dinv, rowptr, csrd, nullptr, nullptr, Ahi, Alo, F_IN, n);
    // GEMM1: (AX) @ W1 + b1, relu -> split bf16 H
    {
        dim3 grid((n + 127) / 128, F_HID / 128);
        gemm_mfma<true><<<grid, 256, 0, stream>>>(Ahi, Alo, W1Thi, W1Tlo, b1, nullptr,
                                                  nullptr, Hhi, Hlo, n, F_HID, F_IN, F_HID);
    }
    // GEMM2: H @ W2, epilogue *dinv -> fp32 Ys (ldc=256)
    {
        dim3 grid((n + 127) / 128, (F_OUT + 127) / 128);
        gemm_mfma<false><<<grid, 256, 0, stream>>>(Hhi, Hlo, W2Thi, W2Tlo, nullptr, dinv,
                                                   bufY, nullptr, nullptr, n, F_OUT, F_HID, 256);
    }
    // L2: aggregate Ys (prescaled) + b2, relu -> out
    agg_kernel<F_OUT, 256, true, false, true><<<nb_agg, 256, 0, stream>>>(
        bufY, dinv, rowptr, csrd, b2, out, nullptr, nullptr, F_OUT, n);
}